// Round 10
// baseline (166.848 us; speedup 1.0000x reference)
//
#include <hip/hip_runtime.h>
#include <hip/hip_bf16.h>

// AggregationMPNN: B=64, N=64, E=16, H=M=OUT=128, 3 passes.
// v10 = v9 with launch_bounds(512,2) everywhere (v9's (512,4) forced VGPR=64 ->
// scratch spills -> 10x slowdown). V2/V3 keep 8 blk/graph + 65KB LDS so 2 blocks/CU
// co-reside from the LDS budget with ~120 VGPRs (<=128 -> 4 waves/SIMD).

typedef __attribute__((ext_vector_type(8))) short short8;
typedef __attribute__((ext_vector_type(4))) float f32x4;

// pk tile map (1 KB tiles; fragment: lane l, j: W[k=kb*32+(l>>4)*8+j][n=nt*16+(l&15)]):
//   [0,64)    Wam [nt16][kb4]
//   [64,256)  GRU [grp4][gate3][nt2][kb8]; col = grp*32 + nt*16 + nb (+gate*128)
//             gate 0/1: kb0-7 over K=256 ([Wi;Wh]). gate 2: kb0-3 Wi_n, kb4-7 Wh_n.
//   [256,288) We  [nt8][kb4]
//   [288,352) Wg  [nt8][kb8] (kb0-3 h-rows, kb4-7 x-rows)
#define PK_TILES 352

__device__ __forceinline__ unsigned short f2bf(float x) {
    unsigned u = __float_as_uint(x);
    u += 0x7FFF + ((u >> 16) & 1);
    return (unsigned short)(u >> 16);
}
__device__ __forceinline__ float bf2f(unsigned short h) {
    return __uint_as_float((unsigned)h << 16);
}
__device__ __forceinline__ float sigmoidf_(float x) { return 1.f / (1.f + __expf(-x)); }
__device__ __forceinline__ f32x4 mfma16(short8 a, short8 b, f32x4 c) {
    return __builtin_amdgcn_mfma_f32_16x16x32_bf16(a, b, c, 0, 0, 0);
}

__global__ __launch_bounds__(512) void fused_prep(
    const float* __restrict__ Wa, const float* __restrict__ Wm,
    const float* __restrict__ Wi, const float* __restrict__ Wh,
    const float* __restrict__ Wg, const float* __restrict__ We,
    unsigned short* __restrict__ pk, int* __restrict__ tick)
{
    if (blockIdx.x == 0 && threadIdx.x < 64) tick[threadIdx.x] = 0;
    int t = (blockIdx.x << 3) + (threadIdx.x >> 6);
    int l = threadIdx.x & 63;
    short8 v8;
#pragma unroll
    for (int j = 0; j < 8; j++) {
        int kk = (l >> 4) * 8 + j;
        int nb = l & 15;
        float x;
        if (t < 64) {
            int nt = t >> 2, kb = t & 3;
            int k = kb * 32 + kk, n = nt * 16 + nb;
            x = (n < 128) ? Wa[k * 128 + n] : Wm[k * 128 + n - 128];
        } else if (t < 256) {
            int u = t - 64;
            int g = u / 48, r1 = u % 48;
            int gate = r1 >> 4, v = r1 & 15;
            int nt = v >> 3, kb = v & 7;
            int k = kb * 32 + kk;
            int col = g * 32 + nt * 16 + nb;
            if (gate == 0)      x = (k < 128) ? Wi[k * 384 + col] : Wh[(k - 128) * 384 + col];
            else if (gate == 1) x = (k < 128) ? Wi[k * 384 + 128 + col] : Wh[(k - 128) * 384 + 128 + col];
            else                x = (k < 128) ? Wi[k * 384 + 256 + col] : Wh[(k - 128) * 384 + 256 + col];
        } else if (t < 288) {
            int u = t - 256; int nt = u >> 2, kb = u & 3;
            x = We[(kb * 32 + kk) * 128 + nt * 16 + nb];
        } else {
            int u = t - 288; int nt = u >> 3, kb = u & 7;
            x = Wg[(kb * 32 + kk) * 128 + nt * 16 + nb];
        }
        v8[j] = (short)f2bf(x);
    }
    *(short8*)&pk[(size_t)t * 512 + l * 8] = v8;
}

// V=1: 256 blocks x 16 rows; h=nodes full, edge scan, full P-GEMM, GRU, project.
// V=2: 512 blocks x 8 rows; load HA/HM/h-own/nbr, GRU, project.
// V=3: 512 blocks x 8 rows; like V=2 but readout partials + ticket reduce.
template <int V>
__global__ __launch_bounds__(512, 2) void pass_k(
    const float* __restrict__ nodes, const float* __restrict__ edges,
    const float* __restrict__ W_att, const float* __restrict__ W_msg,
    const float* __restrict__ b_msg, const float* __restrict__ b_i,
    const float* __restrict__ b_h, const float* __restrict__ b_gate,
    const float* __restrict__ b_emb, const unsigned short* __restrict__ pk,
    unsigned short* __restrict__ nbr_g, int* __restrict__ deg_g,
    float* __restrict__ h_g, unsigned short* __restrict__ hA_g,
    float* __restrict__ hM_g, float* __restrict__ part,
    int* __restrict__ tick, float* __restrict__ out)
{
    // LDS byte offsets, per variant
    constexpr int ROWS = (V == 1) ? 16 : 8;          // rows owned per block
    constexpr int OHLO = (V == 1) ? 16384 : 4096;
    constexpr int OHA  = (V == 1) ? 32768 : 8192;    // [64][128] bf16 linear
    constexpr int OMGH = OHA;                        // overlay after HA dead
    constexpr int OMGL = OHA + 4096;
    constexpr int OHM  = (V == 1) ? 49152 : 24576;   // [64][128] f32 linear
    constexpr int OWB  = 81920;                      // V1 only: Wam staging
    constexpr int OWAE = (V == 1) ? 147456 : 57344;
    constexpr int OWME = OWAE + 4096;
    constexpr int ONBR = OWAE + 8192;
    constexpr int ODEG = ONBR + ((V == 1) ? 2048 : 1024);
    constexpr int LBYTES = ODEG + 64;
    __shared__ __align__(16) char lds[LBYTES];

    const int tid = threadIdx.x;
    const int w = tid >> 6, l = tid & 63;
    const int b   = (V == 1) ? (blockIdx.x >> 2) : (blockIdx.x >> 3);
    const int sub = (V == 1) ? (blockIdx.x & 3) : (blockIdx.x & 7);
    const int HB  = (V == 1) ? sub * 16 : 0;         // own-row base inside LDS h
    const int rbase = b * 64 + sub * ROWS;           // global node row base
    int* degp = (int*)(lds + ODEG);

    // ---- concurrent start loads ----
    if (V == 1) {
        // h = nodes, full 64 rows -> hi/lo swizzled
        int hrow = tid >> 3, hc0 = (tid & 7) * 16;
        float fv[16];
        const float4* hp = (const float4*)&nodes[(size_t)b * 8192 + hrow * 128 + hc0];
#pragma unroll
        for (int q = 0; q < 4; q++) *(float4*)&fv[q * 4] = hp[q];
#pragma unroll
        for (int q = 0; q < 2; q++) {
            short8 sh, sl;
#pragma unroll
            for (int j = 0; j < 8; j++) {
                float v = fv[q * 8 + j];
                unsigned short hh = f2bf(v);
                sh[j] = (short)hh;
                sl[j] = (short)f2bf(v - bf2f(hh));
            }
            int byt = (hc0 * 2 + q * 16) ^ ((hrow & 7) << 4);
            *(short8*)(lds + hrow * 256 + byt) = sh;
            *(short8*)(lds + OHLO + hrow * 256 + byt) = sl;
        }
        // Wam staging (4x cross-wave reuse in P-GEMM)
        short8 wamv[8];
#pragma unroll
        for (int r2 = 0; r2 < 8; r2++)
            wamv[r2] = *(const short8*)&pk[r2 * 4096 + tid * 8];
#pragma unroll
        for (int r2 = 0; r2 < 8; r2++)
            *(short8*)(lds + OWB + (r2 * 4096 + tid * 8) * 2) = wamv[r2];
        // adjacency scan: own 16 rows; LDS + global (indexed by global row)
#pragma unroll
        for (int rr = 0; rr < 2; rr++) {
            int iloc = w * 2 + rr;
            int grow_ = rbase + iloc;
            const float4* ep = (const float4*)&edges[(size_t)(grow_ * 64 + l) * 16];
            int et = -1;
#pragma unroll
            for (int q = 0; q < 4; q++) {
                float4 v = ep[q];
                if (v.x > 0.5f) et = q * 4 + 0;
                if (v.y > 0.5f) et = q * 4 + 1;
                if (v.z > 0.5f) et = q * 4 + 2;
                if (v.w > 0.5f) et = q * 4 + 3;
            }
            unsigned long long mask = __ballot(et >= 0);
            int pos = __popcll(mask & ((1ull << l) - 1ull));
            if (et >= 0) {
                unsigned short ent = (unsigned short)(l | (et << 8));
                *(unsigned short*)(lds + ONBR + (iloc * 64 + pos) * 2) = ent;
                nbr_g[(size_t)grow_ * 64 + pos] = ent;
            }
            if (l == 0) {
                int d = (int)__popcll(mask);
                degp[iloc] = d;
                deg_g[grow_] = d;
            }
        }
    } else {
        // HA full 64 rows (16 KB)
        {
            const short8* src = (const short8*)&hA_g[(size_t)b * 8192];
            *(short8*)(lds + OHA + tid * 32) = src[tid * 2];
            *(short8*)(lds + OHA + tid * 32 + 16) = src[tid * 2 + 1];
        }
        // HM full 64 rows (32 KB)
        {
            const float4* src = (const float4*)&hM_g[(size_t)b * 8192];
#pragma unroll
            for (int q = 0; q < 4; q++)
                *(float4*)(lds + OHM + tid * 64 + q * 16) = src[tid * 4 + q];
        }
        // own 8 h rows -> hi/lo swizzled
        {
            int row = tid >> 6, c0 = (tid & 63) * 2;
            float2 hv = *(const float2*)&h_g[(size_t)(rbase + row) * 128 + c0];
            unsigned short h0 = f2bf(hv.x), h1 = f2bf(hv.y);
            unsigned short g0 = f2bf(hv.x - bf2f(h0)), g1 = f2bf(hv.y - bf2f(h1));
            int byt = (c0 * 2) ^ ((row & 7) << 4);
            *(unsigned*)(lds + row * 256 + byt) = (unsigned)h0 | ((unsigned)h1 << 16);
            *(unsigned*)(lds + OHLO + row * 256 + byt) = (unsigned)g0 | ((unsigned)g1 << 16);
        }
        // nbr 8 rows (1 KB) + deg
        if (tid < 256)
            ((unsigned*)(lds + ONBR))[tid] = ((const unsigned*)(nbr_g + (size_t)rbase * 64))[tid];
        if (tid < 8) degp[tid] = deg_g[rbase + tid];
        else if (tid < 16) degp[tid] = 0;
    }
    // edge-type weight rows -> bf16 pairs
    {
        float2 waev[2], wmev[2];
#pragma unroll
        for (int it = 0; it < 2; it++) {
            waev[it] = *(const float2*)&W_att[16384 + (tid + it * 512) * 2];
            wmev[it] = *(const float2*)&W_msg[16384 + (tid + it * 512) * 2];
        }
#pragma unroll
        for (int it = 0; it < 2; it++) {
            int idx = tid + it * 512;
            *(unsigned*)(lds + OWAE + idx * 4) =
                (unsigned)f2bf(waev[it].x) | ((unsigned)f2bf(waev[it].y) << 16);
            *(unsigned*)(lds + OWME + idx * 4) =
                (unsigned)f2bf(wmev[it].x) | ((unsigned)f2bf(wmev[it].y) << 16);
        }
    }
    const int colw = w * 16 + (l & 15);
    const float bir = b_i[colw] + b_h[colw];
    const float biz = b_i[128 + colw] + b_h[128 + colw];
    const float bin = b_i[256 + colw];
    const float bhn = b_h[256 + colw];
    const float bm0 = b_msg[2 * l], bm1 = b_msg[2 * l + 1];
    __syncthreads();

    // ===== V1 only: P-GEMM [HA|HM] = h @ Wam (64x256) =====
    if (V == 1) {
        const int rowt = w & 3, colh = w >> 2;
        const int arow = rowt * 16 + (l & 15);
        const int rowb = rowt * 16 + (l >> 4) * 4;
        short8 ah[4], al[4];
#pragma unroll
        for (int kb = 0; kb < 4; kb++) {
            int byt = arow * 256 + ((kb * 64 + ((l >> 4) * 16)) ^ ((arow & 7) << 4));
            ah[kb] = *(const short8*)(lds + byt);
            al[kb] = *(const short8*)(lds + OHLO + byt);
        }
#pragma unroll
        for (int nt2 = 0; nt2 < 8; nt2++) {
            int nt = colh * 8 + nt2;
            f32x4 acc = {0.f, 0.f, 0.f, 0.f};
#pragma unroll
            for (int kb = 0; kb < 4; kb++) {
                short8 bf = *(const short8*)(lds + OWB + (nt * 4 + kb) * 1024 + l * 16);
                acc = mfma16(ah[kb], bf, acc);
                acc = mfma16(al[kb], bf, acc);
            }
            int col = nt * 16 + (l & 15);
            if (nt < 8) {
#pragma unroll
                for (int r = 0; r < 4; r++)
                    *(unsigned short*)(lds + OHA + (rowb + r) * 256 + col * 2) = f2bf(acc[r]);
            } else {
#pragma unroll
                for (int r = 0; r < 4; r++)
                    *(float*)(lds + OHM + (rowb + r) * 512 + (col - 128) * 4) = acc[r];
            }
        }
        __syncthreads();
    }

    // ===== attention: V1 2 rows/wave, V2/V3 1 row/wave; 2 channels/lane =====
    constexpr int RPW = (V == 1) ? 2 : 1;
    float resv[2 * RPW];
    {
        const unsigned short* nbrp = (const unsigned short*)(lds + ONBR);
#pragma unroll
        for (int rr = 0; rr < RPW; rr++) {
            int iloc = w * RPW + rr;
            int d = degp[iloc];
            float sw0 = 0.f, sw1 = 0.f, a0 = 0.f, a1 = 0.f;
            for (int k = 0; k < d; k++) {
                int pkt = nbrp[iloc * 64 + k];
                int j = pkt & 63, e = pkt >> 8;
                unsigned ha = *(const unsigned*)(lds + OHA + j * 256 + 4 * l);
                float2 hm = *(const float2*)(lds + OHM + j * 512 + 8 * l);
                unsigned wa2 = *(const unsigned*)(lds + OWAE + (e * 64 + l) * 4);
                unsigned wm2 = *(const unsigned*)(lds + OWME + (e * 64 + l) * 4);
                float e0 = bf2f((unsigned short)ha) + bf2f((unsigned short)wa2);
                float e1 = bf2f((unsigned short)(ha >> 16)) + bf2f((unsigned short)(wa2 >> 16));
                float w0 = __expf(e0), w1 = __expf(e1);
                sw0 += w0; sw1 += w1;
                a0 += w0 * (hm.x + bf2f((unsigned short)wm2));
                a1 += w1 * (hm.y + bf2f((unsigned short)(wm2 >> 16)));
            }
            resv[2 * rr]     = d ? a0 / sw0 + bm0 : 0.f;
            resv[2 * rr + 1] = d ? a1 / sw1 + bm1 : 0.f;
        }
    }
    __syncthreads();   // HA/HM reads done before mg overlays HA
#pragma unroll
    for (int rr = 0; rr < RPW; rr++) {
        int iloc = w * RPW + rr;
        float r0 = resv[2 * rr], r1 = resv[2 * rr + 1];
        unsigned short h0 = f2bf(r0), h1 = f2bf(r1);
        unsigned short g0 = f2bf(r0 - bf2f(h0)), g1 = f2bf(r1 - bf2f(h1));
        int byt = (4 * l) ^ ((iloc & 7) << 4);
        *(unsigned*)(lds + OMGH + iloc * 256 + byt) = (unsigned)h0 | ((unsigned)h1 << 16);
        *(unsigned*)(lds + OMGL + iloc * 256 + byt) = (unsigned)g0 | ((unsigned)g1 << 16);
    }
    __syncthreads();

    // ===== GRU: wave w owns cols [w*16,w*16+16); rows >= ROWS garbage (masked) =====
    {
        const int gbase = 64 + (w >> 1) * 48;
        const int ntc8 = (w & 1) * 8;
        short8 br[8], bz[8], bni[4], bnh[4];
#pragma unroll
        for (int kb = 0; kb < 8; kb++) {
            br[kb] = *(const short8*)&pk[(size_t)(gbase + ntc8 + kb) * 512 + l * 8];
            bz[kb] = *(const short8*)&pk[(size_t)(gbase + 16 + ntc8 + kb) * 512 + l * 8];
        }
#pragma unroll
        for (int kb = 0; kb < 4; kb++) {
            bni[kb] = *(const short8*)&pk[(size_t)(gbase + 32 + ntc8 + kb) * 512 + l * 8];
            bnh[kb] = *(const short8*)&pk[(size_t)(gbase + 32 + ntc8 + 4 + kb) * 512 + l * 8];
        }
        const int lr = l & 15;
        const int hrow2 = HB + lr;
        short8 mh[4], ml[4], hh2[4], hl2[4];
#pragma unroll
        for (int kb = 0; kb < 4; kb++) {
            int sw2 = kb * 64 + ((l >> 4) * 16);
            mh[kb]  = *(const short8*)(lds + OMGH + lr * 256 + (sw2 ^ ((lr & 7) << 4)));
            ml[kb]  = *(const short8*)(lds + OMGL + lr * 256 + (sw2 ^ ((lr & 7) << 4)));
            hh2[kb] = *(const short8*)(lds + hrow2 * 256 + (sw2 ^ ((hrow2 & 7) << 4)));
            hl2[kb] = *(const short8*)(lds + OHLO + hrow2 * 256 + (sw2 ^ ((hrow2 & 7) << 4)));
        }
        f32x4 ar = {0,0,0,0}, az = {0,0,0,0}, ani = {0,0,0,0}, anh = {0,0,0,0};
#pragma unroll
        for (int kb = 0; kb < 4; kb++) {
            ar  = mfma16(mh[kb], br[kb], ar);   ar  = mfma16(ml[kb], br[kb], ar);
            az  = mfma16(mh[kb], bz[kb], az);   az  = mfma16(ml[kb], bz[kb], az);
            ani = mfma16(mh[kb], bni[kb], ani); ani = mfma16(ml[kb], bni[kb], ani);
            anh = mfma16(hh2[kb], bnh[kb], anh); anh = mfma16(hl2[kb], bnh[kb], anh);
        }
#pragma unroll
        for (int kb = 4; kb < 8; kb++) {
            ar = mfma16(hh2[kb - 4], br[kb], ar); ar = mfma16(hl2[kb - 4], br[kb], ar);
            az = mfma16(hh2[kb - 4], bz[kb], az); az = mfma16(hl2[kb - 4], bz[kb], az);
        }
        float hnv[4];
        int rowv[4], bytv[4];
#pragma unroll
        for (int r = 0; r < 4; r++) {
            int row = (l >> 4) * 4 + r;           // local 0..15
            int hr = HB + row;
            int byt = (colw * 2) ^ ((hr & 7) << 4);
            rowv[r] = row; bytv[r] = byt;
            float hold = bf2f(*(unsigned short*)(lds + hr * 256 + byt))
                       + bf2f(*(unsigned short*)(lds + OHLO + hr * 256 + byt));
            float hn = hold;
            if (degp[row] > 0) {
                float rg = sigmoidf_(ar[r] + bir);
                float zg = sigmoidf_(az[r] + biz);
                float ng = tanhf(ani[r] + bin + rg * (anh[r] + bhn));
                hn = (1.f - zg) * ng + zg * hold;
            }
            hnv[r] = hn;
        }
        __syncthreads();   // all h/mg reads complete before overwrite
#pragma unroll
        for (int r = 0; r < 4; r++) {
            if (rowv[r] < ROWS) {
                float hn = hnv[r];
                int hr = HB + rowv[r];
                unsigned short h16 = f2bf(hn);
                *(unsigned short*)(lds + hr * 256 + bytv[r]) = h16;
                *(unsigned short*)(lds + OHLO + hr * 256 + bytv[r]) = f2bf(hn - bf2f(h16));
                if (V < 3)
                    h_g[(size_t)(rbase + rowv[r]) * 128 + colw] = hn;
            }
        }
    }
    __syncthreads();   // updated own-h visible to all waves

    if (V < 3) {
        // ===== project own rows: h_new @ Wam; B direct (tiles unique per wave) =====
        const int lr = l & 15;
        const int hrow2 = HB + lr;
        short8 ph[4], pl2[4];
#pragma unroll
        for (int kb = 0; kb < 4; kb++) {
            int sw2 = kb * 64 + ((l >> 4) * 16);
            ph[kb]  = *(const short8*)(lds + hrow2 * 256 + (sw2 ^ ((hrow2 & 7) << 4)));
            pl2[kb] = *(const short8*)(lds + OHLO + hrow2 * 256 + (sw2 ^ ((hrow2 & 7) << 4)));
        }
        f32x4 aA = {0,0,0,0}, aM = {0,0,0,0};
#pragma unroll
        for (int kb = 0; kb < 4; kb++) {
            short8 b1 = *(const short8*)&pk[(size_t)(w * 4 + kb) * 512 + l * 8];
            short8 b2 = *(const short8*)&pk[(size_t)((w + 8) * 4 + kb) * 512 + l * 8];
            aA = mfma16(ph[kb], b1, aA); aA = mfma16(pl2[kb], b1, aA);
            aM = mfma16(ph[kb], b2, aM); aM = mfma16(pl2[kb], b2, aM);
        }
        int ca = w * 16 + (l & 15);
#pragma unroll
        for (int r = 0; r < 4; r++) {
            int rowloc = (l >> 4) * 4 + r;
            if (rowloc < ROWS) {
                size_t gi = (size_t)b * 8192 + (sub * ROWS + rowloc) * 128 + ca;
                hA_g[gi] = f2bf(aA[r]);
                hM_g[gi] = aM[r];
            }
        }
    } else {
        // ===== readout partials + ticket reduce =====
        const int lr = l & 15;
        short8 rh[4], rl[4], xh[4], xl[4];
#pragma unroll
        for (int kb = 0; kb < 4; kb++) {
            int sw2 = kb * 64 + ((l >> 4) * 16);
            rh[kb] = *(const short8*)(lds + lr * 256 + (sw2 ^ ((lr & 7) << 4)));
            rl[kb] = *(const short8*)(lds + OHLO + lr * 256 + (sw2 ^ ((lr & 7) << 4)));
            const float* p = nodes + (size_t)(rbase + (lr & 7)) * 128 + kb * 32 + (l >> 4) * 8;
            short8 vh, vl;
#pragma unroll
            for (int j = 0; j < 8; j++) {
                float v = p[j];
                unsigned short hv = f2bf(v);
                vh[j] = (short)hv;
                vl[j] = (short)f2bf(v - bf2f(hv));
            }
            xh[kb] = vh; xl[kb] = vl;
        }
        short8 be4[4], bg8[8];
#pragma unroll
        for (int kb = 0; kb < 4; kb++)
            be4[kb] = *(const short8*)&pk[(size_t)(256 + w * 4 + kb) * 512 + l * 8];
#pragma unroll
        for (int kb = 0; kb < 8; kb++)
            bg8[kb] = *(const short8*)&pk[(size_t)(288 + w * 8 + kb) * 512 + l * 8];
        f32x4 ae = {0,0,0,0}, ag = {0,0,0,0};
#pragma unroll
        for (int kb = 0; kb < 4; kb++) {
            ae = mfma16(rh[kb], be4[kb], ae);     ae = mfma16(rl[kb], be4[kb], ae);
            ag = mfma16(rh[kb], bg8[kb], ag);     ag = mfma16(rl[kb], bg8[kb], ag);
            ag = mfma16(xh[kb], bg8[4 + kb], ag); ag = mfma16(xl[kb], bg8[4 + kb], ag);
        }
        float bev = b_emb[colw], bgv = b_gate[colw];
        float s = 0.f;
#pragma unroll
        for (int r = 0; r < 4; r++)
            if (degp[(l >> 4) * 4 + r] > 0)
                s += sigmoidf_(ag[r] + bgv) * (ae[r] + bev);
        s += __shfl_xor(s, 16);
        s += __shfl_xor(s, 32);
        if (l < 16) part[(size_t)blockIdx.x * 128 + w * 16 + l] = s;

        __threadfence();
        __syncthreads();
        __shared__ int lastf;
        if (tid == 0) lastf = (atomicAdd(&tick[b], 1) == 7) ? 1 : 0;
        __syncthreads();
        if (lastf) {
            __threadfence();   // acquire: see other blocks' part writes
            if (tid < 128) {
                float acc = 0.f;
#pragma unroll
                for (int q = 0; q < 8; q++)
                    acc += part[(size_t)(b * 8 + q) * 128 + tid];
                out[(size_t)b * 128 + tid] = acc;
            }
        }
    }
}

extern "C" void kernel_launch(void* const* d_in, const int* in_sizes, int n_in,
                              void* d_out, int out_size, void* d_ws, size_t ws_size,
                              hipStream_t stream) {
    const float* nodes  = (const float*)d_in[0];
    const float* edges  = (const float*)d_in[1];
    const float* W_att  = (const float*)d_in[2];
    const float* W_msg  = (const float*)d_in[4];
    const float* b_msg  = (const float*)d_in[5];
    const float* W_i    = (const float*)d_in[6];
    const float* b_i    = (const float*)d_in[7];
    const float* W_h    = (const float*)d_in[8];
    const float* b_h    = (const float*)d_in[9];
    const float* W_gate = (const float*)d_in[10];
    const float* b_gate = (const float*)d_in[11];
    const float* W_emb  = (const float*)d_in[12];
    const float* b_emb  = (const float*)d_in[13];
    float* out = (float*)d_out;

    char* ws = (char*)d_ws;
    unsigned short* pk    = (unsigned short*)ws; ws += (size_t)PK_TILES * 512 * 2;  // 352 KB
    unsigned short* nbr_g = (unsigned short*)ws; ws += (size_t)4096 * 64 * 2;       // 512 KB
    int*   deg_g = (int*)ws;            ws += 4096 * 4;                             // 16 KB
    float* h_g   = (float*)ws;          ws += (size_t)4096 * 128 * 4;               // 2 MB
    unsigned short* hA_g = (unsigned short*)ws; ws += (size_t)4096 * 128 * 2;       // 1 MB
    float* hM_g  = (float*)ws;          ws += (size_t)4096 * 128 * 4;               // 2 MB
    float* part  = (float*)ws;          ws += (size_t)512 * 128 * 4;                // 256 KB
    int*   tick  = (int*)ws;            ws += 64 * 4;

    fused_prep<<<44, 512, 0, stream>>>(W_att, W_msg, W_i, W_h, W_gate, W_emb, pk, tick);
    pass_k<1><<<256, 512, 0, stream>>>(nodes, edges, W_att, W_msg, b_msg, b_i, b_h,
                                       b_gate, b_emb, pk, nbr_g, deg_g, h_g, hA_g, hM_g,
                                       part, tick, out);
    pass_k<2><<<512, 512, 0, stream>>>(nodes, edges, W_att, W_msg, b_msg, b_i, b_h,
                                       b_gate, b_emb, pk, nbr_g, deg_g, h_g, hA_g, hM_g,
                                       part, tick, out);
    pass_k<3><<<512, 512, 0, stream>>>(nodes, edges, W_att, W_msg, b_msg, b_i, b_h,
                                       b_gate, b_emb, pk, nbr_g, deg_g, h_g, hA_g, hM_g,
                                       part, tick, out);
}

// Round 11
// 52.534 us; speedup vs baseline: 3.1760x; 3.1760x over previous
//
#include <hip/hip_runtime.h>
#include <hip/hip_bf16.h>

// AggregationMPNN: B=64, N=64, E=16, H=M=OUT=128, 3 passes.
// v11 = v8 (52.6us, known-good codegen) + ONE change: per-variant LDS layout.
// V2/V3 drop the V1-only Wam staging buffer + 64-row h region -> 67,648 B LDS
// -> 2 blocks/CU co-reside (load latency of one block hides under compute of the
// other). Body/grid/dispatch structure byte-identical to v8 otherwise.

typedef __attribute__((ext_vector_type(8))) short short8;
typedef __attribute__((ext_vector_type(4))) float f32x4;
typedef __attribute__((ext_vector_type(4))) unsigned short us4;

// pk tile map (1 KB tiles; fragment: lane l, j: W[k=kb*32+(l>>4)*8+j][n=nt*16+(l&15)]):
//   [0,64)    Wam [nt16][kb4]
//   [64,256)  GRU [grp4][gate3][nt2][kb8]; col = grp*32 + nt*16 + nb (+gate*128)
//             gate 0/1: kb0-7 over K=256 ([Wi;Wh]). gate 2: kb0-3 Wi_n, kb4-7 Wh_n.
//   [256,288) We  [nt8][kb4]
//   [288,352) Wg  [nt8][kb8] (kb0-3 h-rows, kb4-7 x-rows)
#define PK_TILES 352

__device__ __forceinline__ unsigned short f2bf(float x) {
    unsigned u = __float_as_uint(x);
    u += 0x7FFF + ((u >> 16) & 1);
    return (unsigned short)(u >> 16);
}
__device__ __forceinline__ float bf2f(unsigned short h) {
    return __uint_as_float((unsigned)h << 16);
}
__device__ __forceinline__ float sigmoidf_(float x) { return 1.f / (1.f + __expf(-x)); }
__device__ __forceinline__ f32x4 mfma16(short8 a, short8 b, f32x4 c) {
    return __builtin_amdgcn_mfma_f32_16x16x32_bf16(a, b, c, 0, 0, 0);
}

__global__ __launch_bounds__(512) void fused_prep(
    const float* __restrict__ Wa, const float* __restrict__ Wm,
    const float* __restrict__ Wi, const float* __restrict__ Wh,
    const float* __restrict__ Wg, const float* __restrict__ We,
    unsigned short* __restrict__ pk)
{
    int t = (blockIdx.x << 3) + (threadIdx.x >> 6);
    int l = threadIdx.x & 63;
    short8 v8;
#pragma unroll
    for (int j = 0; j < 8; j++) {
        int kk = (l >> 4) * 8 + j;
        int nb = l & 15;
        float x;
        if (t < 64) {
            int nt = t >> 2, kb = t & 3;
            int k = kb * 32 + kk, n = nt * 16 + nb;
            x = (n < 128) ? Wa[k * 128 + n] : Wm[k * 128 + n - 128];
        } else if (t < 256) {
            int u = t - 64;
            int g = u / 48, r1 = u % 48;
            int gate = r1 >> 4, v = r1 & 15;
            int nt = v >> 3, kb = v & 7;
            int k = kb * 32 + kk;
            int col = g * 32 + nt * 16 + nb;
            if (gate == 0)      x = (k < 128) ? Wi[k * 384 + col] : Wh[(k - 128) * 384 + col];
            else if (gate == 1) x = (k < 128) ? Wi[k * 384 + 128 + col] : Wh[(k - 128) * 384 + 128 + col];
            else                x = (k < 128) ? Wi[k * 384 + 256 + col] : Wh[(k - 128) * 384 + 256 + col];
        } else if (t < 288) {
            int u = t - 256; int nt = u >> 2, kb = u & 3;
            x = We[(kb * 32 + kk) * 128 + nt * 16 + nb];
        } else {
            int u = t - 288; int nt = u >> 3, kb = u & 7;
            x = Wg[(kb * 32 + kk) * 128 + nt * 16 + nb];
        }
        v8[j] = (short)f2bf(x);
    }
    *(short8*)&pk[(size_t)t * 512 + l * 8] = v8;
}

// V=1: h=nodes full 64 rows, edge scan, full P-GEMM, GRU, project own rows.
// V=2: load HA/HM/h-own/nbr from global, GRU, project own rows.
// V=3: like V=2 but readout partials instead of projection.
// All variants: 256 blocks (4/graph), 16 rows per block. Body identical to v8.
template <int V>
__global__ __launch_bounds__(512, 2) void pass_k(
    const float* __restrict__ nodes, const float* __restrict__ edges,
    const float* __restrict__ W_att, const float* __restrict__ W_msg,
    const float* __restrict__ b_msg, const float* __restrict__ b_i,
    const float* __restrict__ b_h, const float* __restrict__ b_gate,
    const float* __restrict__ b_emb, const unsigned short* __restrict__ pk,
    unsigned short* __restrict__ nbr_g, int* __restrict__ deg_g,
    float* __restrict__ h_g, unsigned short* __restrict__ hA_g,
    float* __restrict__ hM_g, float* __restrict__ part)
{
    // Per-variant LDS layout. V1 matches v8 exactly; V2/V3 pack tight (no OWB,
    // 16-row h region) -> 67,648 B -> 2 blocks/CU.
    constexpr int OHLO = (V == 1) ? 16384 : 4096;    // h hi at 0, lo here
    constexpr int OHA  = (V == 1) ? 32768 : 8192;    // bf16 [64][128] linear
    constexpr int OMGH = OHA;                        // overlay after HA dead
    constexpr int OMGL = OHA + 4096;
    constexpr int OHM  = (V == 1) ? 49152 : 24576;   // f32 [64][128] linear
    constexpr int OWB  = 81920;                      // V1 only: Wam staging
    constexpr int OWAE = (V == 1) ? 147456 : 57344;
    constexpr int OWME = OWAE + 4096;
    constexpr int ONBR = OWAE + 8192;
    constexpr int ODEG = ONBR + 2048;
    constexpr int LBYTES = ODEG + 64;
    __shared__ __align__(16) char lds[LBYTES];

    const int tid = threadIdx.x;
    const int w = tid >> 6, l = tid & 63;
    const int b = blockIdx.x >> 2, sub = blockIdx.x & 3;
    const int HB = (V == 1) ? sub * 16 : 0;          // own-row base inside LDS h
    int* degp = (int*)(lds + ODEG);

    // ---- concurrent start loads ----
    if (V == 1) {
        // h = nodes, full 64 rows -> hi/lo swizzled
        int hrow = tid >> 3, hc0 = (tid & 7) * 16;
        float fv[16];
        const float4* hp = (const float4*)&nodes[(size_t)b * 8192 + hrow * 128 + hc0];
#pragma unroll
        for (int q = 0; q < 4; q++) *(float4*)&fv[q * 4] = hp[q];
#pragma unroll
        for (int q = 0; q < 2; q++) {
            short8 sh, sl;
#pragma unroll
            for (int j = 0; j < 8; j++) {
                float v = fv[q * 8 + j];
                unsigned short hh = f2bf(v);
                sh[j] = (short)hh;
                sl[j] = (short)f2bf(v - bf2f(hh));
            }
            int byt = (hc0 * 2 + q * 16) ^ ((hrow & 7) << 4);
            *(short8*)(lds + hrow * 256 + byt) = sh;
            *(short8*)(lds + OHLO + hrow * 256 + byt) = sl;
        }
        // Wam staging (4x cross-wave reuse in P-GEMM)
        short8 wamv[8];
#pragma unroll
        for (int r2 = 0; r2 < 8; r2++)
            wamv[r2] = *(const short8*)&pk[r2 * 4096 + tid * 8];
#pragma unroll
        for (int r2 = 0; r2 < 8; r2++)
            *(short8*)(lds + OWB + (r2 * 4096 + tid * 8) * 2) = wamv[r2];
        // adjacency scan: own 16 rows; LDS + global
#pragma unroll
        for (int rr = 0; rr < 2; rr++) {
            int iloc = w * 2 + rr;
            int grow_ = b * 64 + sub * 16 + iloc;
            const float4* ep = (const float4*)&edges[(size_t)(grow_ * 64 + l) * 16];
            int et = -1;
#pragma unroll
            for (int q = 0; q < 4; q++) {
                float4 v = ep[q];
                if (v.x > 0.5f) et = q * 4 + 0;
                if (v.y > 0.5f) et = q * 4 + 1;
                if (v.z > 0.5f) et = q * 4 + 2;
                if (v.w > 0.5f) et = q * 4 + 3;
            }
            unsigned long long mask = __ballot(et >= 0);
            int pos = __popcll(mask & ((1ull << l) - 1ull));
            if (et >= 0) {
                unsigned short ent = (unsigned short)(l | (et << 8));
                *(unsigned short*)(lds + ONBR + (iloc * 64 + pos) * 2) = ent;
                nbr_g[(size_t)blockIdx.x * 1024 + iloc * 64 + pos] = ent;
            }
            if (l == 0) {
                int d = (int)__popcll(mask);
                degp[iloc] = d;
                deg_g[grow_] = d;
            }
        }
    } else {
        // HA full (16 KB)
        {
            const short8* src = (const short8*)&hA_g[(size_t)b * 8192];
            short8 v0 = src[tid * 2], v1 = src[tid * 2 + 1];
            *(short8*)(lds + OHA + tid * 32) = v0;
            *(short8*)(lds + OHA + tid * 32 + 16) = v1;
        }
        // HM full (32 KB)
        {
            const float4* src = (const float4*)&hM_g[(size_t)b * 8192];
#pragma unroll
            for (int q = 0; q < 4; q++)
                *(float4*)(lds + OHM + tid * 64 + q * 16) = src[tid * 4 + q];
        }
        // own h rows (16x128 f32) -> hi/lo swizzled rows 0..15
        {
            int row = tid >> 5, c0 = (tid & 31) * 4;
            float4 hv = *(const float4*)&h_g[(size_t)(b * 64 + sub * 16 + row) * 128 + c0];
            us4 hi4, lo4;
            float vv[4] = {hv.x, hv.y, hv.z, hv.w};
#pragma unroll
            for (int j = 0; j < 4; j++) {
                unsigned short hh = f2bf(vv[j]);
                hi4[j] = hh;
                lo4[j] = f2bf(vv[j] - bf2f(hh));
            }
            int byt = (c0 * 2) ^ ((row & 7) << 4);
            *(us4*)(lds + row * 256 + byt) = hi4;
            *(us4*)(lds + OHLO + row * 256 + byt) = lo4;
        }
        // nbr (2 KB) + deg
        *(unsigned*)(lds + ONBR + tid * 4) =
            ((const unsigned*)(nbr_g + (size_t)blockIdx.x * 1024))[tid];
        if (tid < 16) degp[tid] = deg_g[b * 64 + sub * 16 + tid];
    }
    // edge-type weight rows -> bf16 pairs
    {
        float2 waev[2], wmev[2];
#pragma unroll
        for (int it = 0; it < 2; it++) {
            waev[it] = *(const float2*)&W_att[16384 + (tid + it * 512) * 2];
            wmev[it] = *(const float2*)&W_msg[16384 + (tid + it * 512) * 2];
        }
#pragma unroll
        for (int it = 0; it < 2; it++) {
            int idx = tid + it * 512;
            *(unsigned*)(lds + OWAE + idx * 4) =
                (unsigned)f2bf(waev[it].x) | ((unsigned)f2bf(waev[it].y) << 16);
            *(unsigned*)(lds + OWME + idx * 4) =
                (unsigned)f2bf(wmev[it].x) | ((unsigned)f2bf(wmev[it].y) << 16);
        }
    }
    const int colw = w * 16 + (l & 15);
    const float bir = b_i[colw] + b_h[colw];
    const float biz = b_i[128 + colw] + b_h[128 + colw];
    const float bin = b_i[256 + colw];
    const float bhn = b_h[256 + colw];
    const float bm0 = b_msg[2 * l], bm1 = b_msg[2 * l + 1];
    __syncthreads();

    // ===== V1 only: P-GEMM [HA|HM] = h @ Wam (64x256) =====
    if (V == 1) {
        const int rowt = w & 3, colh = w >> 2;
        const int arow = rowt * 16 + (l & 15);
        const int rowb = rowt * 16 + (l >> 4) * 4;
        short8 ah[4], al[4];
#pragma unroll
        for (int kb = 0; kb < 4; kb++) {
            int byt = arow * 256 + ((kb * 64 + ((l >> 4) * 16)) ^ ((arow & 7) << 4));
            ah[kb] = *(const short8*)(lds + byt);
            al[kb] = *(const short8*)(lds + OHLO + byt);
        }
#pragma unroll
        for (int nt2 = 0; nt2 < 8; nt2++) {
            int nt = colh * 8 + nt2;
            f32x4 acc = {0.f, 0.f, 0.f, 0.f};
#pragma unroll
            for (int kb = 0; kb < 4; kb++) {
                short8 bf = *(const short8*)(lds + OWB + (nt * 4 + kb) * 1024 + l * 16);
                acc = mfma16(ah[kb], bf, acc);
                acc = mfma16(al[kb], bf, acc);
            }
            int col = nt * 16 + (l & 15);
            if (nt < 8) {
#pragma unroll
                for (int r = 0; r < 4; r++)
                    *(unsigned short*)(lds + OHA + (rowb + r) * 256 + col * 2) = f2bf(acc[r]);
            } else {
#pragma unroll
                for (int r = 0; r < 4; r++)
                    *(float*)(lds + OHM + (rowb + r) * 512 + (col - 128) * 4) = acc[r];
            }
        }
        __syncthreads();
    }

    // ===== attention: wave w -> local rows 2w, 2w+1; 2 channels/lane =====
    float resv[4];
    {
        const unsigned short* nbrp = (const unsigned short*)(lds + ONBR);
#pragma unroll
        for (int rr = 0; rr < 2; rr++) {
            int iloc = w * 2 + rr;
            int d = degp[iloc];
            float sw0 = 0.f, sw1 = 0.f, a0 = 0.f, a1 = 0.f;
            for (int k = 0; k < d; k++) {
                int pkt = nbrp[iloc * 64 + k];
                int j = pkt & 63, e = pkt >> 8;
                unsigned ha = *(const unsigned*)(lds + OHA + j * 256 + 4 * l);
                float2 hm = *(const float2*)(lds + OHM + j * 512 + 8 * l);
                unsigned wa2 = *(const unsigned*)(lds + OWAE + (e * 64 + l) * 4);
                unsigned wm2 = *(const unsigned*)(lds + OWME + (e * 64 + l) * 4);
                float e0 = bf2f((unsigned short)ha) + bf2f((unsigned short)wa2);
                float e1 = bf2f((unsigned short)(ha >> 16)) + bf2f((unsigned short)(wa2 >> 16));
                float w0 = __expf(e0), w1 = __expf(e1);
                sw0 += w0; sw1 += w1;
                a0 += w0 * (hm.x + bf2f((unsigned short)wm2));
                a1 += w1 * (hm.y + bf2f((unsigned short)(wm2 >> 16)));
            }
            resv[2 * rr]     = d ? a0 / sw0 + bm0 : 0.f;
            resv[2 * rr + 1] = d ? a1 / sw1 + bm1 : 0.f;
        }
    }
    __syncthreads();   // HA/HM reads done before mg overlays HA
#pragma unroll
    for (int rr = 0; rr < 2; rr++) {
        int iloc = w * 2 + rr;
        float r0 = resv[2 * rr], r1 = resv[2 * rr + 1];
        unsigned short h0 = f2bf(r0), h1 = f2bf(r1);
        unsigned short g0 = f2bf(r0 - bf2f(h0)), g1 = f2bf(r1 - bf2f(h1));
        int byt = (4 * l) ^ ((iloc & 7) << 4);
        *(unsigned*)(lds + OMGH + iloc * 256 + byt) = (unsigned)h0 | ((unsigned)h1 << 16);
        *(unsigned*)(lds + OMGL + iloc * 256 + byt) = (unsigned)g0 | ((unsigned)g1 << 16);
    }
    __syncthreads();

    // ===== GRU: wave w owns cols [w*16,w*16+16) for all gates; B direct global =====
    {
        const int gbase = 64 + (w >> 1) * 48;
        const int ntc8 = (w & 1) * 8;
        short8 br[8], bz[8], bni[4], bnh[4];
#pragma unroll
        for (int kb = 0; kb < 8; kb++) {
            br[kb] = *(const short8*)&pk[(size_t)(gbase + ntc8 + kb) * 512 + l * 8];
            bz[kb] = *(const short8*)&pk[(size_t)(gbase + 16 + ntc8 + kb) * 512 + l * 8];
        }
#pragma unroll
        for (int kb = 0; kb < 4; kb++) {
            bni[kb] = *(const short8*)&pk[(size_t)(gbase + 32 + ntc8 + kb) * 512 + l * 8];
            bnh[kb] = *(const short8*)&pk[(size_t)(gbase + 32 + ntc8 + 4 + kb) * 512 + l * 8];
        }
        const int lr = l & 15;
        const int hrow2 = HB + lr;
        short8 mh[4], ml[4], hh2[4], hl2[4];
#pragma unroll
        for (int kb = 0; kb < 4; kb++) {
            int sw2 = kb * 64 + ((l >> 4) * 16);
            mh[kb]  = *(const short8*)(lds + OMGH + lr * 256 + (sw2 ^ ((lr & 7) << 4)));
            ml[kb]  = *(const short8*)(lds + OMGL + lr * 256 + (sw2 ^ ((lr & 7) << 4)));
            hh2[kb] = *(const short8*)(lds + hrow2 * 256 + (sw2 ^ ((hrow2 & 7) << 4)));
            hl2[kb] = *(const short8*)(lds + OHLO + hrow2 * 256 + (sw2 ^ ((hrow2 & 7) << 4)));
        }
        f32x4 ar = {0,0,0,0}, az = {0,0,0,0}, ani = {0,0,0,0}, anh = {0,0,0,0};
#pragma unroll
        for (int kb = 0; kb < 4; kb++) {
            ar  = mfma16(mh[kb], br[kb], ar);   ar  = mfma16(ml[kb], br[kb], ar);
            az  = mfma16(mh[kb], bz[kb], az);   az  = mfma16(ml[kb], bz[kb], az);
            ani = mfma16(mh[kb], bni[kb], ani); ani = mfma16(ml[kb], bni[kb], ani);
            anh = mfma16(hh2[kb], bnh[kb], anh); anh = mfma16(hl2[kb], bnh[kb], anh);
        }
#pragma unroll
        for (int kb = 4; kb < 8; kb++) {
            ar = mfma16(hh2[kb - 4], br[kb], ar); ar = mfma16(hl2[kb - 4], br[kb], ar);
            az = mfma16(hh2[kb - 4], bz[kb], az); az = mfma16(hl2[kb - 4], bz[kb], az);
        }
        // elementwise (all reads of h before barrier; writes after)
        float hnv[4];
        int rowv[4], bytv[4];
#pragma unroll
        for (int r = 0; r < 4; r++) {
            int row = (l >> 4) * 4 + r;           // local 0..15
            int hr = HB + row;
            int byt = (colw * 2) ^ ((hr & 7) << 4);
            rowv[r] = row; bytv[r] = byt;
            float hold = bf2f(*(unsigned short*)(lds + hr * 256 + byt))
                       + bf2f(*(unsigned short*)(lds + OHLO + hr * 256 + byt));
            float hn = hold;
            if (degp[row] > 0) {
                float rg = sigmoidf_(ar[r] + bir);
                float zg = sigmoidf_(az[r] + biz);
                float ng = tanhf(ani[r] + bin + rg * (anh[r] + bhn));
                hn = (1.f - zg) * ng + zg * hold;
            }
            hnv[r] = hn;
        }
        __syncthreads();   // all h/mg reads complete before overwrite
#pragma unroll
        for (int r = 0; r < 4; r++) {
            float hn = hnv[r];
            int hr = HB + rowv[r];
            unsigned short h16 = f2bf(hn);
            *(unsigned short*)(lds + hr * 256 + bytv[r]) = h16;
            *(unsigned short*)(lds + OHLO + hr * 256 + bytv[r]) = f2bf(hn - bf2f(h16));
            if (V < 3)
                h_g[(size_t)(b * 64 + sub * 16 + rowv[r]) * 128 + colw] = hn;
        }
    }
    __syncthreads();   // updated own-h visible to all waves

    if (V < 3) {
        // ===== project own 16 rows: h_new @ Wam; B direct (tiles unique per wave) =====
        const int lr = l & 15;
        const int hrow2 = HB + lr;
        short8 ph[4], pl2[4];
#pragma unroll
        for (int kb = 0; kb < 4; kb++) {
            int sw2 = kb * 64 + ((l >> 4) * 16);
            ph[kb]  = *(const short8*)(lds + hrow2 * 256 + (sw2 ^ ((hrow2 & 7) << 4)));
            pl2[kb] = *(const short8*)(lds + OHLO + hrow2 * 256 + (sw2 ^ ((hrow2 & 7) << 4)));
        }
        f32x4 aA = {0,0,0,0}, aM = {0,0,0,0};
#pragma unroll
        for (int kb = 0; kb < 4; kb++) {
            short8 b1 = *(const short8*)&pk[(size_t)(w * 4 + kb) * 512 + l * 8];
            short8 b2 = *(const short8*)&pk[(size_t)((w + 8) * 4 + kb) * 512 + l * 8];
            aA = mfma16(ph[kb], b1, aA); aA = mfma16(pl2[kb], b1, aA);
            aM = mfma16(ph[kb], b2, aM); aM = mfma16(pl2[kb], b2, aM);
        }
        int ca = w * 16 + (l & 15);
#pragma unroll
        for (int r = 0; r < 4; r++) {
            int rowloc = (l >> 4) * 4 + r;
            size_t gi = (size_t)b * 8192 + (sub * 16 + rowloc) * 128 + ca;
            hA_g[gi] = f2bf(aA[r]);
            hM_g[gi] = aM[r];
        }
    } else {
        // ===== readout partials =====
        const int lr = l & 15;
        short8 rh[4], rl[4], xh[4], xl[4];
#pragma unroll
        for (int kb = 0; kb < 4; kb++) {
            int sw2 = kb * 64 + ((l >> 4) * 16);
            rh[kb] = *(const short8*)(lds + lr * 256 + (sw2 ^ ((lr & 7) << 4)));
            rl[kb] = *(const short8*)(lds + OHLO + lr * 256 + (sw2 ^ ((lr & 7) << 4)));
            const float* p = nodes + (size_t)(b * 64 + sub * 16 + lr) * 128 + kb * 32 + (l >> 4) * 8;
            short8 vh, vl;
#pragma unroll
            for (int j = 0; j < 8; j++) {
                float v = p[j];
                unsigned short hv = f2bf(v);
                vh[j] = (short)hv;
                vl[j] = (short)f2bf(v - bf2f(hv));
            }
            xh[kb] = vh; xl[kb] = vl;
        }
        short8 be4[4], bg8[8];
#pragma unroll
        for (int kb = 0; kb < 4; kb++)
            be4[kb] = *(const short8*)&pk[(size_t)(256 + w * 4 + kb) * 512 + l * 8];
#pragma unroll
        for (int kb = 0; kb < 8; kb++)
            bg8[kb] = *(const short8*)&pk[(size_t)(288 + w * 8 + kb) * 512 + l * 8];
        f32x4 ae = {0,0,0,0}, ag = {0,0,0,0};
#pragma unroll
        for (int kb = 0; kb < 4; kb++) {
            ae = mfma16(rh[kb], be4[kb], ae);     ae = mfma16(rl[kb], be4[kb], ae);
            ag = mfma16(rh[kb], bg8[kb], ag);     ag = mfma16(rl[kb], bg8[kb], ag);
            ag = mfma16(xh[kb], bg8[4 + kb], ag); ag = mfma16(xl[kb], bg8[4 + kb], ag);
        }
        float bev = b_emb[colw], bgv = b_gate[colw];
        float s = 0.f;
#pragma unroll
        for (int r = 0; r < 4; r++)
            if (degp[(l >> 4) * 4 + r] > 0)
                s += sigmoidf_(ag[r] + bgv) * (ae[r] + bev);
        s += __shfl_xor(s, 16);
        s += __shfl_xor(s, 32);
        if (l < 16) part[(size_t)blockIdx.x * 128 + w * 16 + l] = s;
    }
}

__global__ __launch_bounds__(256) void reduce_out(
    const float* __restrict__ part, float* __restrict__ out)
{
    int idx = blockIdx.x * 256 + threadIdx.x;   // 8192
    int b = idx >> 7, c = idx & 127;
    out[idx] = part[(size_t)(b * 4 + 0) * 128 + c] + part[(size_t)(b * 4 + 1) * 128 + c]
             + part[(size_t)(b * 4 + 2) * 128 + c] + part[(size_t)(b * 4 + 3) * 128 + c];
}

extern "C" void kernel_launch(void* const* d_in, const int* in_sizes, int n_in,
                              void* d_out, int out_size, void* d_ws, size_t ws_size,
                              hipStream_t stream) {
    const float* nodes  = (const float*)d_in[0];
    const float* edges  = (const float*)d_in[1];
    const float* W_att  = (const float*)d_in[2];
    const float* W_msg  = (const float*)d_in[4];
    const float* b_msg  = (const float*)d_in[5];
    const float* W_i    = (const float*)d_in[6];
    const float* b_i    = (const float*)d_in[7];
    const float* W_h    = (const float*)d_in[8];
    const float* b_h    = (const float*)d_in[9];
    const float* W_gate = (const float*)d_in[10];
    const float* b_gate = (const float*)d_in[11];
    const float* W_emb  = (const float*)d_in[12];
    const float* b_emb  = (const float*)d_in[13];
    float* out = (float*)d_out;

    char* ws = (char*)d_ws;
    unsigned short* pk    = (unsigned short*)ws; ws += (size_t)PK_TILES * 512 * 2;  // 352 KB
    unsigned short* nbr_g = (unsigned short*)ws; ws += (size_t)256 * 1024 * 2;      // 512 KB
    int*   deg_g = (int*)ws;            ws += 4096 * 4;                             // 16 KB
    float* h_g   = (float*)ws;          ws += (size_t)4096 * 128 * 4;               // 2 MB
    unsigned short* hA_g = (unsigned short*)ws; ws += (size_t)4096 * 128 * 2;       // 1 MB
    float* hM_g  = (float*)ws;          ws += (size_t)4096 * 128 * 4;               // 2 MB
    float* part  = (float*)ws;          ws += (size_t)256 * 128 * 4;                // 128 KB

    fused_prep<<<44, 512, 0, stream>>>(W_att, W_msg, W_i, W_h, W_gate, W_emb, pk);
    pass_k<1><<<256, 512, 0, stream>>>(nodes, edges, W_att, W_msg, b_msg, b_i, b_h,
                                       b_gate, b_emb, pk, nbr_g, deg_g, h_g, hA_g, hM_g, part);
    pass_k<2><<<256, 512, 0, stream>>>(nodes, edges, W_att, W_msg, b_msg, b_i, b_h,
                                       b_gate, b_emb, pk, nbr_g, deg_g, h_g, hA_g, hM_g, part);
    pass_k<3><<<256, 512, 0, stream>>>(nodes, edges, W_att, W_msg, b_msg, b_i, b_h,
                                       b_gate, b_emb, pk, nbr_g, deg_g, h_g, hA_g, hM_g, part);
    reduce_out<<<32, 256, 0, stream>>>(part, out);
}